// Round 2
// baseline (461.894 us; speedup 1.0000x reference)
//
#include <hip/hip_runtime.h>

typedef _Float16 f16;
typedef __attribute__((ext_vector_type(8))) _Float16 f16x8;
typedef __attribute__((ext_vector_type(4))) _Float16 f16x4;
typedef __attribute__((ext_vector_type(4))) float f32x4;

#define BATCH 16
#define NSEQ  2048
#define DDIM  300
#define DPK   328   // padded row length (f16) for row-major Xf/Yf (zeros in [300,328))
#define DPV   304   // padded d-rows for transposed XT/YT (zeros in [300,304))
#define NTP   2056  // padded q-cols for transposed copies (zeros in [2048,2056))
#define XF_ELEMS (BATCH*NSEQ*DPK)
#define XT_ELEMS (BATCH*DPV*NTP)

__device__ __forceinline__ void gl_lds16(const void* g, void* l) {
  __builtin_amdgcn_global_load_lds((const __attribute__((address_space(1))) unsigned int*)g,
                                   (__attribute__((address_space(3))) unsigned int*)l, 16, 0, 0);
}

// ---------------------------------------------------------------------------
// Preprocess: X,Y f32 -> f16 row-major (padded) + f16 transposed (padded)
// ---------------------------------------------------------------------------
__global__ __launch_bounds__(256) void prep_kernel(const float* __restrict__ X,
                                                   const float* __restrict__ Y,
                                                   f16* __restrict__ Xf, f16* __restrict__ Yf,
                                                   f16* __restrict__ XT, f16* __restrict__ YT) {
  __shared__ float tile[32][33];
  int bz   = blockIdx.z;            // 0..31 = tensor*16 + b
  int tsel = bz >> 4, b = bz & 15;
  const float* src = tsel ? Y : X;
  f16* dF = tsel ? Yf : Xf;
  f16* dT = tsel ? YT : XT;
  int d0 = blockIdx.y * 32;
  int q0 = blockIdx.x * 32;
  int tid = threadIdx.x;
  int c = tid & 31, rr = tid >> 5;

  #pragma unroll
  for (int i = 0; i < 4; ++i) {
    int qr = rr + i * 8;
    int q = q0 + qr, d = d0 + c;
    float v = 0.f;
    if (q < NSEQ && d < DDIM) v = src[(size_t)b * NSEQ * DDIM + (size_t)q * DDIM + d];
    tile[c][qr] = v;
    if (q < NSEQ && d < DPK) dF[(size_t)b * NSEQ * DPK + (size_t)q * DPK + d] = (f16)v;
  }
  __syncthreads();
  #pragma unroll
  for (int i = 0; i < 4; ++i) {
    int dr = rr + i * 8;
    int d = d0 + dr, q = q0 + c;
    if (d < DPV && q < NTP) dT[(size_t)b * DPV * NTP + (size_t)d * NTP + q] = (f16)tile[dr][c];
  }
}

// ---------------------------------------------------------------------------
// Flash attention: 4 waves x 32 q-rows (QBLK=128), KV tile 32, fp16 16x16x32.
// Each K/V fragment read feeds 2 MFMAs (2 Q-frags) -> LDS-balanced vs MFMA.
// Grid = 2*16*16 = 512 blocks -> exactly 2 blocks/CU, XCD-chunk swizzled.
// ---------------------------------------------------------------------------
__global__ __launch_bounds__(256, 2) void attn_kernel(const f16* __restrict__ Xf,
                                                      const f16* __restrict__ Yf,
                                                      const f16* __restrict__ XT,
                                                      const f16* __restrict__ YT,
                                                      float* __restrict__ out) {
  __shared__ __align__(16) f16 Ksh[32][DPK];    // 20992 B
  __shared__ __align__(16) f16 VTsh[DPV][32];   // 19456 B (no pad: cols = kv)
  __shared__ __align__(16) f16 Pl[4][32][32];   //  8192 B  (total 48640 B -> 2 blocks/CU)

  int idx = blockIdx.x;
  int swz = (idx & 7) * 64 + (idx >> 3);        // 512 % 8 == 0: bijective XCD chunking
  int qt  = swz & 15;
  int b   = (swz >> 4) & 15;
  int dir = swz >> 8;

  const f16* Qsrc = dir ? Yf : Xf;
  const f16* Ksrc = dir ? Xf : Yf;
  const f16* Vts  = dir ? XT : YT;   // V^T source [DPV][NTP]

  const size_t bq = (size_t)b * NSEQ * DPK;
  const size_t bt = (size_t)b * DPV * NTP;

  int tid = threadIdx.x;
  int lane = tid & 63, wid = tid >> 6;
  int l15 = lane & 15, g = lane >> 4;
  int qw = qt * 128 + wid * 32;      // this wave's q base (32 rows)

  // Q fragments: B-operand layout, lane holds Q[q = qi*16 + l15][ks*32 + g*8 + j]
  f16x8 qf[2][10];
  #pragma unroll
  for (int qi = 0; qi < 2; ++qi) {
    const f16* qrow = Qsrc + bq + (size_t)(qw + qi * 16 + l15) * DPK + g * 8;
    #pragma unroll
    for (int ks = 0; ks < 10; ++ks) qf[qi][ks] = *(const f16x8*)(qrow + ks * 32);
  }

  f32x4 O[19][2];
  #pragma unroll
  for (int dt = 0; dt < 19; ++dt) {
    O[dt][0] = (f32x4){0.f, 0.f, 0.f, 0.f};
    O[dt][1] = (f32x4){0.f, 0.f, 0.f, 0.f};
  }
  float m[2] = {-3.0e38f, -3.0e38f}, lsum[2] = {0.f, 0.f};

  const char* gK0 = (const char*)(Ksrc + bq);
  const char* gV0 = (const char*)(Vts + bt);

  #pragma unroll 1
  for (int t = 0; t < 64; ++t) {
    int kv0 = t * 32;
    // ---- stage K tile: contiguous 32 x 656B = 1312 chunks of 16B
    {
      const char* gK = gK0 + (size_t)t * 20992;
      #pragma unroll
      for (int i = 0; i < 6; ++i) {
        int c = i * 256 + tid;
        if (c < 1312) gl_lds16(gK + c * 16, (char*)&Ksh[0][0] + c * 16);
      }
      // ---- stage V^T tile: 304 rows x 64B = 1216 chunks (row = c>>2, slot = c&3)
      #pragma unroll
      for (int i = 0; i < 5; ++i) {
        int c = i * 256 + tid;
        if (c < 1216) {
          const char* ga = gV0 + (size_t)(c >> 2) * (NTP * 2) + kv0 * 2 + (c & 3) * 16;
          gl_lds16(ga, (char*)&VTsh[0][0] + c * 16);
        }
      }
    }
    asm volatile("s_waitcnt vmcnt(0)" ::: "memory");
    __syncthreads();

    // ---- QK^T (swapped): S^T[kv][q] — each K-frag read feeds both Q-frags
    f32x4 S[2][2];
    S[0][0] = (f32x4){0.f,0.f,0.f,0.f}; S[0][1] = (f32x4){0.f,0.f,0.f,0.f};
    S[1][0] = (f32x4){0.f,0.f,0.f,0.f}; S[1][1] = (f32x4){0.f,0.f,0.f,0.f};
    #pragma unroll
    for (int ks = 0; ks < 10; ++ks) {
      f16x8 af0 = *(const f16x8*)&Ksh[l15][ks * 32 + g * 8];
      f16x8 af1 = *(const f16x8*)&Ksh[16 + l15][ks * 32 + g * 8];
      S[0][0] = __builtin_amdgcn_mfma_f32_16x16x32_f16(af0, qf[0][ks], S[0][0], 0, 0, 0);
      S[0][1] = __builtin_amdgcn_mfma_f32_16x16x32_f16(af0, qf[1][ks], S[0][1], 0, 0, 0);
      S[1][0] = __builtin_amdgcn_mfma_f32_16x16x32_f16(af1, qf[0][ks], S[1][0], 0, 0, 0);
      S[1][1] = __builtin_amdgcn_mfma_f32_16x16x32_f16(af1, qf[1][ks], S[1][1], 0, 0, 0);
    }

    // ---- online softmax per q-frag (q-col = l15; lane rows kv = kvt*16 + 4g + r)
    #pragma unroll
    for (int qi = 0; qi < 2; ++qi) {
      float t0 = fmaxf(fmaxf(S[0][qi][0], S[0][qi][1]), fmaxf(S[0][qi][2], S[0][qi][3]));
      float t1 = fmaxf(fmaxf(S[1][qi][0], S[1][qi][1]), fmaxf(S[1][qi][2], S[1][qi][3]));
      float tmax = fmaxf(t0, t1);
      tmax = fmaxf(tmax, __shfl_xor(tmax, 16, 64));
      tmax = fmaxf(tmax, __shfl_xor(tmax, 32, 64));
      if (__any(tmax > m[qi] + 8.0f)) {          // defer-max
        float mnew = fmaxf(m[qi], tmax);
        float al = __expf(m[qi] - mnew);
        lsum[qi] *= al;
        #pragma unroll
        for (int dt = 0; dt < 19; ++dt) {
          O[dt][qi][0] *= al; O[dt][qi][1] *= al;
          O[dt][qi][2] *= al; O[dt][qi][3] *= al;
        }
        m[qi] = mnew;
      }
      float ts = 0.f;
      f16x4 ph0, ph1;
      #pragma unroll
      for (int r = 0; r < 4; ++r) {
        float e0 = __expf(S[0][qi][r] - m[qi]);  // bounded by e^8
        float e1 = __expf(S[1][qi][r] - m[qi]);
        ph0[r] = (f16)e0; ph1[r] = (f16)e1;
        ts += e0 + e1;
      }
      *(f16x4*)&Pl[wid][qi * 16 + l15][g * 4]      = ph0;  // kvt=0
      *(f16x4*)&Pl[wid][qi * 16 + l15][16 + g * 4] = ph1;  // kvt=1
      ts += __shfl_xor(ts, 16, 64);
      ts += __shfl_xor(ts, 32, 64);
      lsum[qi] += ts;
    }
    asm volatile("s_waitcnt lgkmcnt(0)" ::: "memory");

    // ---- PV (swapped): O^T[d][q] += V^T . P^T — each V-frag feeds both Q-frags
    f16x8 pb0 = *(const f16x8*)&Pl[wid][l15][g * 8];
    f16x8 pb1 = *(const f16x8*)&Pl[wid][16 + l15][g * 8];
    #pragma unroll
    for (int dt = 0; dt < 19; ++dt) {
      f16x8 vf = *(const f16x8*)&VTsh[dt * 16 + l15][g * 8];
      O[dt][0] = __builtin_amdgcn_mfma_f32_16x16x32_f16(vf, pb0, O[dt][0], 0, 0, 0);
      O[dt][1] = __builtin_amdgcn_mfma_f32_16x16x32_f16(vf, pb1, O[dt][1], 0, 0, 0);
    }
    __syncthreads();
  }

  // ---- epilogue: O /= l, multiply by input row (f16 row-major copy), store f32x4
  #pragma unroll
  for (int qi = 0; qi < 2; ++qi) {
    float rinv = 1.0f / lsum[qi];
    int q = qw + qi * 16 + l15;
    const f16* mrow = Qsrc + bq + (size_t)q * DPK;
    size_t orow = (size_t)b * (4096 * 300) + (size_t)(dir * 2048 + q) * 300;
    #pragma unroll
    for (int dt = 0; dt < 19; ++dt) {
      if (dt < 18 || g < 3) {                    // d = dt*16 + 4g + r < 300
        f16x4 mu = *(const f16x4*)(mrow + dt * 16 + g * 4);
        f32x4 o;
        o[0] = O[dt][qi][0] * rinv * (float)mu[0];
        o[1] = O[dt][qi][1] * rinv * (float)mu[1];
        o[2] = O[dt][qi][2] * rinv * (float)mu[2];
        o[3] = O[dt][qi][3] * rinv * (float)mu[3];
        *(f32x4*)&out[orow + dt * 16 + g * 4] = o;
      }
    }
  }
}

extern "C" void kernel_launch(void* const* d_in, const int* in_sizes, int n_in,
                              void* d_out, int out_size, void* d_ws, size_t ws_size,
                              hipStream_t stream) {
  const float* X = (const float*)d_in[0];
  const float* Y = (const float*)d_in[1];
  float* out = (float*)d_out;

  size_t need = (size_t)(2 * XF_ELEMS + 2 * XT_ELEMS) * sizeof(f16);  // ~83 MB
  if (ws_size < need) return;

  f16* Xf = (f16*)d_ws;
  f16* Yf = Xf + XF_ELEMS;
  f16* XT = Yf + XF_ELEMS;
  f16* YT = XT + XT_ELEMS;

  prep_kernel<<<dim3(65, 11, 32), 256, 0, stream>>>(X, Y, Xf, Yf, XT, YT);
  attn_kernel<<<dim3(512), 256, 0, stream>>>(Xf, Yf, XT, YT, out);
}

// Round 3
// 363.153 us; speedup vs baseline: 1.2719x; 1.2719x over previous
//
#include <hip/hip_runtime.h>

typedef _Float16 f16;
typedef __attribute__((ext_vector_type(8))) _Float16 f16x8;
typedef __attribute__((ext_vector_type(4))) _Float16 f16x4;
typedef __attribute__((ext_vector_type(4))) float f32x4;

#define BATCH 16
#define NSEQ  2048
#define DDIM  300
#define DPK   328   // padded row length (f16) for row-major Xf/Yf (zeros in [300,328))
#define DPV   304   // padded d-rows for transposed XT/YT (zeros in [300,304))
#define NTP   2056  // padded q-cols for transposed copies (zeros in [2048,2056))
#define XF_ELEMS (BATCH*NSEQ*DPK)
#define XT_ELEMS (BATCH*DPV*NTP)

__device__ __forceinline__ void gl_lds16(const void* g, void* l) {
  __builtin_amdgcn_global_load_lds((const __attribute__((address_space(1))) unsigned int*)g,
                                   (__attribute__((address_space(3))) unsigned int*)l, 16, 0, 0);
}

// ---------------------------------------------------------------------------
// Preprocess: X,Y f32 -> f16 row-major (padded) + f16 transposed (padded)
// ---------------------------------------------------------------------------
__global__ __launch_bounds__(256) void prep_kernel(const float* __restrict__ X,
                                                   const float* __restrict__ Y,
                                                   f16* __restrict__ Xf, f16* __restrict__ Yf,
                                                   f16* __restrict__ XT, f16* __restrict__ YT) {
  __shared__ float tile[32][33];
  int bz   = blockIdx.z;            // 0..31 = tensor*16 + b
  int tsel = bz >> 4, b = bz & 15;
  const float* src = tsel ? Y : X;
  f16* dF = tsel ? Yf : Xf;
  f16* dT = tsel ? YT : XT;
  int d0 = blockIdx.y * 32;
  int q0 = blockIdx.x * 32;
  int tid = threadIdx.x;
  int c = tid & 31, rr = tid >> 5;

  #pragma unroll
  for (int i = 0; i < 4; ++i) {
    int qr = rr + i * 8;
    int q = q0 + qr, d = d0 + c;
    float v = 0.f;
    if (q < NSEQ && d < DDIM) v = src[(size_t)b * NSEQ * DDIM + (size_t)q * DDIM + d];
    tile[c][qr] = v;
    if (q < NSEQ && d < DPK) dF[(size_t)b * NSEQ * DPK + (size_t)q * DPK + d] = (f16)v;
  }
  __syncthreads();
  #pragma unroll
  for (int i = 0; i < 4; ++i) {
    int dr = rr + i * 8;
    int d = d0 + dr, q = q0 + c;
    if (d < DPV && q < NTP) dT[(size_t)b * DPV * NTP + (size_t)d * NTP + q] = (f16)tile[dr][c];
  }
}

// ---------------------------------------------------------------------------
// Flash attention: 8 waves = 4 pairs; pair owns 32 q-rows.
// Each member: QK^T + softmax + P for its own 16 q (full K).
// PV d-split across the pair (member0: d 0..159, member1: d 160..303) using a
// shared per-pair P buffer. K/V LDS double-buffered; mid-tile raw s_barrier
// (lgkmcnt only) keeps staging loads in flight; only the end __syncthreads
// drains vmcnt. Grid = 512 blocks, XCD-chunk swizzled.
// ---------------------------------------------------------------------------
__global__ __launch_bounds__(512, 2) void attn_kernel(const f16* __restrict__ Xf,
                                                      const f16* __restrict__ Yf,
                                                      const f16* __restrict__ XT,
                                                      const f16* __restrict__ YT,
                                                      float* __restrict__ out) {
  __shared__ __align__(16) f16 Ksh[2][32][DPK];   // 41984 B (656 B rows: conflict-free)
  __shared__ __align__(16) f16 VTsh[2][DPV][40];  // 48640 B (80 B rows: conflict-free)
  __shared__ __align__(16) f16 Psh[4][32][40];    // 10240 B per-pair P (80 B rows)
  __shared__ float Alx[4][2][16];                 //   512 B rescale/lsum exchange
                                                  // total 101376 B -> 1 block/CU, 8 waves

  int idx = blockIdx.x;
  int swz = (idx & 7) * 64 + (idx >> 3);          // 512 % 8 == 0: bijective XCD chunking
  int qt  = swz & 15;
  int b   = (swz >> 4) & 15;
  int dir = swz >> 8;

  const f16* Qsrc = dir ? Yf : Xf;
  const f16* Ksrc = dir ? Xf : Yf;
  const f16* Vts  = dir ? XT : YT;   // V^T source [DPV][NTP]

  const size_t bq = (size_t)b * NSEQ * DPK;
  const size_t bt = (size_t)b * DPV * NTP;

  int tid = threadIdx.x;
  int lane = tid & 63, wid = tid >> 6;
  int pair = wid >> 1, mem = wid & 1;
  int l15 = lane & 15, g = lane >> 4;
  int qpair = qt * 128 + pair * 32;
  int qown  = qpair + mem * 16;       // this wave's 16 softmax-owned q rows

  // Q fragments for own 16 q, full K: lane holds Q[q=l15][ks*32 + g*8 + j]
  f16x8 qf[10];
  {
    const f16* qrow = Qsrc + bq + (size_t)(qown + l15) * DPK + g * 8;
    #pragma unroll
    for (int ks = 0; ks < 10; ++ks) qf[ks] = *(const f16x8*)(qrow + ks * 32);
  }

  const int dtoff = mem ? 10 : 0;     // PV d-tile range: member0 dt 0..9, member1 10..18
  const int ndt   = mem ? 9 : 10;

  f32x4 O[10][2];                     // O^T[d][q] slices for the pair's 32 q
  #pragma unroll
  for (int dt = 0; dt < 10; ++dt) {
    O[dt][0] = (f32x4){0.f, 0.f, 0.f, 0.f};
    O[dt][1] = (f32x4){0.f, 0.f, 0.f, 0.f};
  }
  float m = -3.0e38f, lsum = 0.f;

  const char* gK0 = (const char*)(Ksrc + bq);
  const char* gV0 = (const char*)(Vts + bt);

  auto stage = [&](int tt, int buf) {
    const char* gK = gK0 + (size_t)tt * (32 * DPK * 2);
    char* lK = (char*)&Ksh[buf][0][0];
    #pragma unroll
    for (int i = 0; i < 3; ++i) {          // 1312 16B chunks of K
      int c = i * 512 + tid;
      if (c < 1312) gl_lds16(gK + c * 16, lK + c * 16);
    }
    const char* gV = gV0 + (size_t)tt * 64;
    char* lV = (char*)&VTsh[buf][0][0];
    #pragma unroll
    for (int i = 0; i < 3; ++i) {          // 304 rows x 5 slots (64B data + 16B overread)
      int c = i * 512 + tid;
      if (c < 1520) {
        int row = c / 5, slot = c - row * 5;
        gl_lds16(gV + (size_t)row * (NTP * 2) + slot * 16, lV + c * 16);
      }
    }
  };

  stage(0, 0);
  __syncthreads();                         // drains vmcnt(0): tile 0 ready

  #pragma unroll 1
  for (int t = 0; t < 64; ++t) {
    int cur = t & 1;
    if (t < 63) stage(t + 1, cur ^ 1);     // issue early; land under this tile's compute

    // ---- QK^T (swapped): S^T[kv][q-own], full K
    f32x4 S0 = (f32x4){0.f,0.f,0.f,0.f}, S1 = (f32x4){0.f,0.f,0.f,0.f};
    __builtin_amdgcn_s_setprio(1);
    #pragma unroll
    for (int ks = 0; ks < 10; ++ks) {
      f16x8 a0 = *(const f16x8*)&Ksh[cur][l15][ks * 32 + g * 8];
      f16x8 a1 = *(const f16x8*)&Ksh[cur][16 + l15][ks * 32 + g * 8];
      S0 = __builtin_amdgcn_mfma_f32_16x16x32_f16(a0, qf[ks], S0, 0, 0, 0);
      S1 = __builtin_amdgcn_mfma_f32_16x16x32_f16(a1, qf[ks], S1, 0, 0, 0);
    }
    __builtin_amdgcn_s_setprio(0);

    // ---- online softmax for own 16 q (q-col = l15; lane rows kv = kvt*16 + 4g + r)
    float t0 = fmaxf(fmaxf(S0[0], S0[1]), fmaxf(S0[2], S0[3]));
    float t1 = fmaxf(fmaxf(S1[0], S1[1]), fmaxf(S1[2], S1[3]));
    float tmax = fmaxf(t0, t1);
    tmax = fmaxf(tmax, __shfl_xor(tmax, 16, 64));
    tmax = fmaxf(tmax, __shfl_xor(tmax, 32, 64));
    float al = 1.0f;
    if (__any(tmax > m + 8.0f)) {          // defer-max
      float mnew = fmaxf(m, tmax);
      al = __expf(m - mnew);
      lsum *= al;
      m = mnew;
    }
    float ts = 0.f;
    f16x4 ph0, ph1;
    #pragma unroll
    for (int r = 0; r < 4; ++r) {
      float e0 = __expf(S0[r] - m);        // bounded by e^8
      float e1 = __expf(S1[r] - m);
      ph0[r] = (f16)e0; ph1[r] = (f16)e1;
      ts += e0 + e1;
    }
    ts += __shfl_xor(ts, 16, 64);
    ts += __shfl_xor(ts, 32, 64);
    lsum += ts;
    *(f16x4*)&Psh[pair][mem * 16 + l15][g * 4]      = ph0;   // kvt 0
    *(f16x4*)&Psh[pair][mem * 16 + l15][16 + g * 4] = ph1;   // kvt 1
    if (g == 0) Alx[pair][mem][l15] = al;

    // ---- P/al exchange: raw barrier, LDS-drain only (staging stays in flight)
    asm volatile("s_waitcnt lgkmcnt(0)" ::: "memory");
    __builtin_amdgcn_s_barrier();
    __builtin_amdgcn_sched_barrier(0);

    float al0 = Alx[pair][0][l15];
    float al1 = Alx[pair][1][l15];
    if (__any((al0 < 1.0f) || (al1 < 1.0f))) {
      #pragma unroll
      for (int dt = 0; dt < 10; ++dt) {
        O[dt][0][0] *= al0; O[dt][0][1] *= al0; O[dt][0][2] *= al0; O[dt][0][3] *= al0;
        O[dt][1][0] *= al1; O[dt][1][1] *= al1; O[dt][1][2] *= al1; O[dt][1][3] *= al1;
      }
    }

    // ---- PV (swapped, d-split): O^T[d][q] += V^T . P^T for pair's 32 q
    f16x8 pb0 = *(const f16x8*)&Psh[pair][l15][g * 8];
    f16x8 pb1 = *(const f16x8*)&Psh[pair][16 + l15][g * 8];
    __builtin_amdgcn_s_setprio(1);
    #pragma unroll
    for (int dt = 0; dt < 10; ++dt) {
      if (dt < ndt) {
        f16x8 vf = *(const f16x8*)&VTsh[cur][(dtoff + dt) * 16 + l15][g * 8];
        O[dt][0] = __builtin_amdgcn_mfma_f32_16x16x32_f16(vf, pb0, O[dt][0], 0, 0, 0);
        O[dt][1] = __builtin_amdgcn_mfma_f32_16x16x32_f16(vf, pb1, O[dt][1], 0, 0, 0);
      }
    }
    __builtin_amdgcn_s_setprio(0);

    __syncthreads();   // full drain: next tile staged + all waves done with buf[cur]
  }

  // ---- epilogue: broadcast lsum within pair, then store d-slices
  if (g == 0) Alx[pair][mem][l15] = lsum;
  asm volatile("s_waitcnt lgkmcnt(0)" ::: "memory");
  __builtin_amdgcn_s_barrier();
  __builtin_amdgcn_sched_barrier(0);
  float ri0 = 1.0f / Alx[pair][0][l15];
  float ri1 = 1.0f / Alx[pair][1][l15];

  #pragma unroll
  for (int qi = 0; qi < 2; ++qi) {
    float rinv = qi ? ri1 : ri0;
    int q = qpair + qi * 16 + l15;
    const f16* mrow = Qsrc + bq + (size_t)q * DPK;
    size_t orow = (size_t)b * (4096 * 300) + (size_t)(dir * 2048 + q) * 300;
    #pragma unroll
    for (int dt = 0; dt < 10; ++dt) {
      if (dt < ndt) {
        int d = (dtoff + dt) * 16 + g * 4;
        if (d < 300) {
          f16x4 mu = *(const f16x4*)(mrow + d);
          f32x4 o;
          o[0] = O[dt][qi][0] * rinv * (float)mu[0];
          o[1] = O[dt][qi][1] * rinv * (float)mu[1];
          o[2] = O[dt][qi][2] * rinv * (float)mu[2];
          o[3] = O[dt][qi][3] * rinv * (float)mu[3];
          *(f32x4*)&out[orow + d] = o;
        }
      }
    }
  }
}

extern "C" void kernel_launch(void* const* d_in, const int* in_sizes, int n_in,
                              void* d_out, int out_size, void* d_ws, size_t ws_size,
                              hipStream_t stream) {
  const float* X = (const float*)d_in[0];
  const float* Y = (const float*)d_in[1];
  float* out = (float*)d_out;

  size_t need = (size_t)(2 * XF_ELEMS + 2 * XT_ELEMS) * sizeof(f16);  // ~83 MB
  if (ws_size < need) return;

  f16* Xf = (f16*)d_ws;
  f16* Yf = Xf + XF_ELEMS;
  f16* XT = Yf + XF_ELEMS;
  f16* YT = XT + XT_ELEMS;

  prep_kernel<<<dim3(65, 11, 32), 256, 0, stream>>>(X, Y, Xf, Yf, XT, YT);
  attn_kernel<<<dim3(512), 512, 0, stream>>>(Xf, Yf, XT, YT, out);
}